// Round 1
// baseline (109.176 us; speedup 1.0000x reference)
//
#include <hip/hip_runtime.h>
#include <math.h>

#define N_DIM 1024
#define C_DIM 256
#define H_DIM 8
#define D_DIM 32
#define TB 8
#define CN (C_DIM * N_DIM)
#define TOT (TB * CN)
#define BN_EPS 1e-5f
#define SCALE 0.1f

__device__ __forceinline__ float mspike(float x) {
    return rintf(fminf(fmaxf(x, 0.f), 4.f)) * 0.25f;
}

__global__ __launch_bounds__(256) void add_spike_kernel(
    const float4* __restrict__ q, const float4* __restrict__ qp,
    float4* __restrict__ tmp, float4* __restrict__ sx) {
    int i = blockIdx.x * 256 + threadIdx.x;
    float4 a = q[i], b = qp[i];
    float4 t = make_float4(a.x + b.x, a.y + b.y, a.z + b.z, a.w + b.w);
    tmp[i] = t;
    sx[i] = make_float4(mspike(t.x), mspike(t.y), mspike(t.z), mspike(t.w));
}

template <int EPI>
__global__ __launch_bounds__(256) void convbn_kernel(
    const float* __restrict__ in_base, const float* __restrict__ Wall,
    const float* __restrict__ cb, const float* __restrict__ gam,
    const float* __restrict__ bet, const float* __restrict__ mn,
    const float* __restrict__ vr, const float* __restrict__ tmp,
    float* __restrict__ out_base) {
    int bz = blockIdx.z;
    int br, tb;
    if (EPI == 0) { br = bz >> 3; tb = bz & 7; }
    else          { br = 3;       tb = bz; }

    const float* A = Wall + br * C_DIM * C_DIM;
    const float* Bm = in_base + (size_t)tb * CN;
    const int m0 = blockIdx.y * 64, n0 = blockIdx.x * 64;

    __shared__ float As[16][68];
    __shared__ float Bs[16][68];

    const int tx = threadIdx.x, ty = threadIdx.y;
    const int tid = ty * 16 + tx;
    const int am = tid >> 2, ak = (tid & 3) << 2;
    const int kb = tid >> 4, jn = (tid & 15) << 2;

    float acc[4][4] = {};

    for (int k0 = 0; k0 < C_DIM; k0 += 16) {
        float4 av = *(const float4*)&A[(m0 + am) * C_DIM + k0 + ak];
        float4 bv = *(const float4*)&Bm[(size_t)(k0 + kb) * N_DIM + n0 + jn];
        As[ak + 0][am] = av.x;
        As[ak + 1][am] = av.y;
        As[ak + 2][am] = av.z;
        As[ak + 3][am] = av.w;
        *(float4*)&Bs[kb][jn] = bv;
        __syncthreads();
#pragma unroll
        for (int kk = 0; kk < 16; ++kk) {
            float4 a = *(const float4*)&As[kk][ty * 4];
            float4 b = *(const float4*)&Bs[kk][tx * 4];
            acc[0][0] += a.x * b.x; acc[0][1] += a.x * b.y;
            acc[0][2] += a.x * b.z; acc[0][3] += a.x * b.w;
            acc[1][0] += a.y * b.x; acc[1][1] += a.y * b.y;
            acc[1][2] += a.y * b.z; acc[1][3] += a.y * b.w;
            acc[2][0] += a.z * b.x; acc[2][1] += a.z * b.y;
            acc[2][2] += a.z * b.z; acc[2][3] += a.z * b.w;
            acc[3][0] += a.w * b.x; acc[3][1] += a.w * b.y;
            acc[3][2] += a.w * b.z; acc[3][3] += a.w * b.w;
        }
        __syncthreads();
    }

#pragma unroll
    for (int i = 0; i < 4; ++i) {
        int c = m0 + ty * 4 + i;
        int gc = br * C_DIM + c;
        float inv = gam[gc] / sqrtf(vr[gc] + BN_EPS);
        float sh = (cb[gc] - mn[gc]) * inv + bet[gc];
        int n = n0 + tx * 4;
        float4 r;
        r.x = acc[i][0] * inv + sh;
        r.y = acc[i][1] * inv + sh;
        r.z = acc[i][2] * inv + sh;
        r.w = acc[i][3] * inv + sh;
        size_t idx = (size_t)tb * CN + (size_t)c * N_DIM + n;
        if (EPI == 0) {
            r.x = mspike(r.x); r.y = mspike(r.y);
            r.z = mspike(r.z); r.w = mspike(r.w);
            *(float4*)&out_base[(size_t)br * TOT + idx] = r;
        } else {
            float4 t = *(const float4*)&tmp[idx];
            r.x += t.x; r.y += t.y; r.z += t.z; r.w += t.w;
            *(float4*)&out_base[idx] = r;
        }
    }
}

__global__ __launch_bounds__(1024) void ktv_kernel(
    const float* __restrict__ sk, const float* __restrict__ sv,
    float* __restrict__ part) {
    const int tbh = blockIdx.x;
    const int ns = blockIdx.y;
    const int tb = tbh >> 3, h = tbh & 7;
    const int t = threadIdx.x;
    const int d1 = t >> 5, d2 = t & 31;

    __shared__ float kt[32][133];
    __shared__ float vt[32][133];

    const float* kbase = sk + (size_t)tb * CN + (size_t)(h * D_DIM) * N_DIM;
    const float* vbase = sv + (size_t)tb * CN + (size_t)(h * D_DIM) * N_DIM;

    const int r = t >> 5, nn = (t & 31) << 2;
    float acc = 0.f;
    for (int c0 = ns * 256; c0 < ns * 256 + 256; c0 += 128) {
        float4 kv4 = *(const float4*)&kbase[(size_t)r * N_DIM + c0 + nn];
        float4 vv4 = *(const float4*)&vbase[(size_t)r * N_DIM + c0 + nn];
        kt[r][nn] = kv4.x; kt[r][nn + 1] = kv4.y; kt[r][nn + 2] = kv4.z; kt[r][nn + 3] = kv4.w;
        vt[r][nn] = vv4.x; vt[r][nn + 1] = vv4.y; vt[r][nn + 2] = vv4.z; vt[r][nn + 3] = vv4.w;
        __syncthreads();
#pragma unroll 8
        for (int j = 0; j < 128; ++j) acc += kt[d1][j] * vt[d2][j];
        __syncthreads();
    }
    part[(size_t)(ns * 64 + tbh) * 1024 + t] = acc;
}

__global__ __launch_bounds__(256) void ov_kernel(
    const float* __restrict__ sq, const float* __restrict__ part,
    float* __restrict__ so) {
    const int tbh = blockIdx.x;
    const int nc = blockIdx.y;
    const int tb = tbh >> 3, h = tbh & 7;
    const int t = threadIdx.x;

    __shared__ float kv[32][33];
    for (int e = t; e < 1024; e += 256) {
        float s = 0.f;
#pragma unroll
        for (int ns = 0; ns < 4; ++ns)
            s += part[(size_t)(ns * 64 + tbh) * 1024 + e];
        kv[e >> 5][e & 31] = s;
    }
    __syncthreads();

    const int n = nc * 256 + t;
    const float* qbase = sq + (size_t)tb * CN + (size_t)(h * D_DIM) * N_DIM;
    float acc[32] = {};
#pragma unroll 4
    for (int d1 = 0; d1 < 32; ++d1) {
        float qv = qbase[(size_t)d1 * N_DIM + n];
#pragma unroll
        for (int d = 0; d < 32; ++d) acc[d] += kv[d1][d] * qv;
    }
    float* obase = so + (size_t)tb * CN + (size_t)(h * D_DIM) * N_DIM;
#pragma unroll
    for (int d = 0; d < 32; ++d)
        obase[(size_t)d * N_DIM + n] = mspike(SCALE * acc[d]);
}

extern "C" void kernel_launch(void* const* d_in, const int* in_sizes, int n_in,
                              void* d_out, int out_size, void* d_ws, size_t ws_size,
                              hipStream_t stream) {
    const float* query = (const float*)d_in[0];
    const float* qpos  = (const float*)d_in[3];
    const float* convw = (const float*)d_in[4];
    const float* convb = (const float*)d_in[5];
    const float* gam   = (const float*)d_in[6];
    const float* bet   = (const float*)d_in[7];
    const float* mn    = (const float*)d_in[8];
    const float* vr    = (const float*)d_in[9];
    float* out = (float*)d_out;

    float* f = (float*)d_ws;
    float* tmp  = f;
    float* sx   = f + (size_t)TOT;
    float* sq   = f + (size_t)2 * TOT;
    float* sk   = f + (size_t)3 * TOT;
    float* sv   = f + (size_t)4 * TOT;
    float* part = f + (size_t)5 * TOT;
    float* so   = sx;  // sx dead after branch convs

    add_spike_kernel<<<TOT / 4 / 256, 256, 0, stream>>>(
        (const float4*)query, (const float4*)qpos, (float4*)tmp, (float4*)sx);

    {
        dim3 grid(N_DIM / 64, C_DIM / 64, 24), block(16, 16);
        convbn_kernel<0><<<grid, block, 0, stream>>>(
            sx, convw, convb, gam, bet, mn, vr, nullptr, sq);
    }
    {
        dim3 grid(64, 4);
        ktv_kernel<<<grid, 1024, 0, stream>>>(sk, sv, part);
    }
    {
        dim3 grid(64, 4);
        ov_kernel<<<grid, 256, 0, stream>>>(sq, part, so);
    }
    {
        dim3 grid(N_DIM / 64, C_DIM / 64, 8), block(16, 16);
        convbn_kernel<1><<<grid, block, 0, stream>>>(
            so, convw, convb, gam, bet, mn, vr, tmp, out);
    }
}

// Round 2
// 64.499 us; speedup vs baseline: 1.6927x; 1.6927x over previous
//
#include <hip/hip_runtime.h>
#include <hip/hip_bf16.h>
#include <math.h>

#define N_DIM 1024
#define C_DIM 256
#define CN (C_DIM * N_DIM)
#define TOT (8 * CN)
#define BN_EPS 1e-5f
#define SCALE 0.1f

typedef short short8 __attribute__((ext_vector_type(8)));
typedef float f32x4 __attribute__((ext_vector_type(4)));

__device__ __forceinline__ float mspike(float x) {
    return rintf(fminf(fmaxf(x, 0.f), 4.f)) * 0.25f;
}
__device__ __forceinline__ unsigned short bfbits(float x) {
    __hip_bfloat16 h = __float2bfloat16(x);
    return *reinterpret_cast<unsigned short*>(&h);
}
__device__ __forceinline__ f32x4 mfma16(short8 a, short8 b, f32x4 c) {
    return __builtin_amdgcn_mfma_f32_16x16x32_bf16(a, b, c, 0, 0, 0);
}
__device__ __forceinline__ void async16(void* lds, const void* g) {
    __builtin_amdgcn_global_load_lds(
        (const __attribute__((address_space(1))) void*)g,
        (__attribute__((address_space(3))) void*)lds, 16, 0, 0);
}

// ---------- prep: W -> [W_hi | W_lo] bf16 (4,256,512); BN folded ----------
__global__ __launch_bounds__(64) void prep_kernel(
    const float* __restrict__ w, const float* __restrict__ cb,
    const float* __restrict__ g, const float* __restrict__ bet,
    const float* __restrict__ mn, const float* __restrict__ vr,
    unsigned short* __restrict__ whl, float* __restrict__ bninv,
    float* __restrict__ bnsh) {
    int row = blockIdx.x;  // br*256 + c_out
    int t = threadIdx.x;
    float4 wv = *(const float4*)&w[(size_t)row * 256 + t * 4];
    float xs[4] = {wv.x, wv.y, wv.z, wv.w};
    unsigned short hi[4], lo[4];
#pragma unroll
    for (int j = 0; j < 4; ++j) {
        __hip_bfloat16 h = __float2bfloat16(xs[j]);
        float hf = __bfloat162float(h);
        __hip_bfloat16 l = __float2bfloat16(xs[j] - hf);
        hi[j] = *(unsigned short*)&h;
        lo[j] = *(unsigned short*)&l;
    }
    size_t base = (size_t)row * 512;
    *(ushort4*)&whl[base + t * 4] = make_ushort4(hi[0], hi[1], hi[2], hi[3]);
    *(ushort4*)&whl[base + 256 + t * 4] = make_ushort4(lo[0], lo[1], lo[2], lo[3]);
    if (t == 0) {
        float inv = g[row] / sqrtf(vr[row] + BN_EPS);
        bninv[row] = inv;
        bnsh[row] = (cb[row] - mn[row]) * inv + bet[row];
    }
}

// ---------- add+spike+transpose: tmp f32 (c,n); sxT bf16 (n,c) ------------
__global__ __launch_bounds__(256) void add_spike_kernel(
    const float* __restrict__ q, const float* __restrict__ qp,
    float* __restrict__ tmp, unsigned short* __restrict__ sxT) {
    __shared__ float ld[64][65];
    int tb = blockIdx.z, c0 = blockIdx.y * 64, n0 = blockIdx.x * 64;
    int t = threadIdx.x;
    int cl = t >> 4, nl = (t & 15) * 4;
    size_t base = (size_t)tb * CN;
#pragma unroll
    for (int r = 0; r < 4; ++r) {
        int c = cl + r * 16;
        size_t off = base + (size_t)(c0 + c) * N_DIM + n0 + nl;
        float4 a = *(const float4*)&q[off];
        float4 b = *(const float4*)&qp[off];
        float4 s = make_float4(a.x + b.x, a.y + b.y, a.z + b.z, a.w + b.w);
        *(float4*)&tmp[off] = s;
        ld[c][nl] = mspike(s.x); ld[c][nl + 1] = mspike(s.y);
        ld[c][nl + 2] = mspike(s.z); ld[c][nl + 3] = mspike(s.w);
    }
    __syncthreads();
    int nl2 = t >> 2, cg = (t & 3) * 16;
    size_t ob = base + (size_t)(n0 + nl2) * C_DIM + c0 + cg;
#pragma unroll
    for (int j = 0; j < 8; ++j) {
        ushort2 u = make_ushort2(bfbits(ld[cg + 2 * j][nl2]),
                                 bfbits(ld[cg + 2 * j + 1][nl2]));
        *(ushort2*)&sxT[ob + 2 * j] = u;
    }
}

// ---------- MFMA conv_bn: D = W_hl @ X (ORIENT1) or X^T @ W_hl^T (ORIENT2)
// ORIENT1: A=Whl rows=c_out(M=256), B=actT rows=n(N=1024); out n-major bf16 (q)
// ORIENT2: A=actT rows=n(M=1024), B=Whl rows=c_out(N=256); out d-major
//          EPI0 -> bf16 spiked (k/v); EPI1 -> f32 + tmp residual (final out)
template <int ORIENT, int EPI>
__global__ __launch_bounds__(256) void convbn_mfma(
    const unsigned short* __restrict__ whl,
    const unsigned short* __restrict__ actT,
    const float* __restrict__ bninv, const float* __restrict__ bnsh,
    unsigned short* __restrict__ dq, unsigned short* __restrict__ dk,
    unsigned short* __restrict__ dv, const float* __restrict__ tmp,
    float* __restrict__ outf) {
    __shared__ short At[2][128 * 64];
    __shared__ short Bt[2][128 * 64];
    int bz = blockIdx.z;
    int br, tb, mt, nt;
    if (ORIENT == 1) {            // 128 blocks: tb*16 + mt*8 + nt
        br = 0; nt = bz & 7; mt = (bz >> 3) & 1; tb = bz >> 4;
    } else if (EPI == 0) {        // 256 blocks: br1*128 + tb*16 + mt*2 + nt
        nt = bz & 1; mt = (bz >> 1) & 7; tb = (bz >> 4) & 7; br = 1 + (bz >> 7);
    } else {                      // 128 blocks: tb*16 + mt*2 + nt
        nt = bz & 1; mt = (bz >> 1) & 7; tb = bz >> 4; br = 3;
    }
    const int m0 = mt * 128, n0 = nt * 128;
    const int tid = threadIdx.x;
    const int lane = tid & 63, wid = tid >> 6;
    const int wm = wid >> 1, wn = wid & 1;
    const int l15 = lane & 15, l4 = lane >> 4;

    const unsigned short* wbase = whl + (size_t)br * 131072;
    const unsigned short* abase = actT + (size_t)tb * CN;

    f32x4 acc[4][4];
    f32x4 z = {0.f, 0.f, 0.f, 0.f};
#pragma unroll
    for (int i = 0; i < 4; ++i)
#pragma unroll
        for (int j = 0; j < 4; ++j) acc[i][j] = z;

    // stage k-tile kt into buffer buf (pre-swizzled source, linear LDS dest)
    auto stage = [&](int buf, int kt) {
        int k0w = kt * 64;
        int k0a = (kt * 64) & 255;
#pragma unroll
        for (int c = 0; c < 4; ++c) {
            int s = c * 256 + tid;
            int row = s >> 3;
            int kb = (((s & 7) ^ (row & 7)) << 3);
            const unsigned short *ga, *gb;
            if (ORIENT == 1) {
                ga = wbase + (size_t)(m0 + row) * 512 + k0w + kb;
                gb = abase + (size_t)(n0 + row) * 256 + k0a + kb;
            } else {
                ga = abase + (size_t)(m0 + row) * 256 + k0a + kb;
                gb = wbase + (size_t)(n0 + row) * 512 + k0w + kb;
            }
            async16(&At[buf][s * 8], ga);
            async16(&Bt[buf][s * 8], gb);
        }
    };

    stage(0, 0);
    __syncthreads();
    int cur = 0;
    for (int kt = 0; kt < 8; ++kt) {
        if (kt < 7) stage(cur ^ 1, kt + 1);
#pragma unroll
        for (int kk = 0; kk < 2; ++kk) {
            short8 af[4], bf[4];
#pragma unroll
            for (int f = 0; f < 4; ++f) {
                int rowa = wm * 64 + f * 16 + l15;
                int ka = ((kk * 4 + l4) ^ (rowa & 7)) << 4;
                af[f] = *(const short8*)((const char*)&At[cur][0] + rowa * 128 + ka);
                int rowb = wn * 64 + f * 16 + l15;
                int kb2 = ((kk * 4 + l4) ^ (rowb & 7)) << 4;
                bf[f] = *(const short8*)((const char*)&Bt[cur][0] + rowb * 128 + kb2);
            }
#pragma unroll
            for (int i = 0; i < 4; ++i)
#pragma unroll
                for (int j = 0; j < 4; ++j)
                    acc[i][j] = mfma16(af[i], bf[j], acc[i][j]);
        }
        __syncthreads();
        cur ^= 1;
    }

    if (ORIENT == 1) {
#pragma unroll
        for (int i = 0; i < 4; ++i) {
            int cb4 = m0 + wm * 64 + i * 16 + l4 * 4;
            float4 inv = *(const float4*)&bninv[cb4];
            float4 sh = *(const float4*)&bnsh[cb4];
#pragma unroll
            for (int j = 0; j < 4; ++j) {
                int n = n0 + wn * 64 + j * 16 + l15;
                f32x4 a = acc[i][j];
                ushort4 u;
                u.x = bfbits(mspike(a[0] * inv.x + sh.x));
                u.y = bfbits(mspike(a[1] * inv.y + sh.y));
                u.z = bfbits(mspike(a[2] * inv.z + sh.z));
                u.w = bfbits(mspike(a[3] * inv.w + sh.w));
                *(ushort4*)&dq[(size_t)tb * CN + (size_t)n * C_DIM + cb4] = u;
            }
        }
    } else {
#pragma unroll
        for (int j = 0; j < 4; ++j) {
            int c = n0 + wn * 64 + j * 16 + l15;
            float inv = bninv[br * 256 + c];
            float sh = bnsh[br * 256 + c];
#pragma unroll
            for (int i = 0; i < 4; ++i) {
                int nb4 = m0 + wm * 64 + i * 16 + l4 * 4;
                f32x4 a = acc[i][j];
                size_t off = (size_t)tb * CN + (size_t)c * N_DIM + nb4;
                if (EPI == 0) {
                    ushort4 u;
                    u.x = bfbits(mspike(a[0] * inv + sh));
                    u.y = bfbits(mspike(a[1] * inv + sh));
                    u.z = bfbits(mspike(a[2] * inv + sh));
                    u.w = bfbits(mspike(a[3] * inv + sh));
                    unsigned short* dst = (br == 1) ? dk : dv;
                    *(ushort4*)&dst[off] = u;
                } else {
                    float4 t4 = *(const float4*)&tmp[off];
                    float4 o;
                    o.x = a[0] * inv + sh + t4.x;
                    o.y = a[1] * inv + sh + t4.y;
                    o.z = a[2] * inv + sh + t4.z;
                    o.w = a[3] * inv + sh + t4.w;
                    *(float4*)&outf[off] = o;
                }
            }
        }
    }
}

// ---------- fused attention: kTv (exact) then o = mspike(0.1 * kTv^T q) ----
__global__ __launch_bounds__(256) void attn_kernel(
    const unsigned short* __restrict__ skD, const unsigned short* __restrict__ svD,
    const unsigned short* __restrict__ sqT, unsigned short* __restrict__ soT) {
    __shared__ float pbuf[4][32][33];
    __shared__ unsigned short aop[64][32];  // [k_eff][c]: hi rows 0-31, lo 32-63
    int tb = blockIdx.x >> 3, h = blockIdx.x & 7;
    int tid = threadIdx.x, lane = tid & 63, w = tid >> 6;
    int l15 = lane & 15, l4 = lane >> 4;
    const unsigned short* kb = skD + (size_t)tb * CN + (size_t)h * 32 * N_DIM;
    const unsigned short* vb = svD + (size_t)tb * CN + (size_t)h * 32 * N_DIM;

    // phase 1: kTv, wave w covers n in [w*256, w*256+256)
    f32x4 acc[2][2];
    f32x4 z = {0.f, 0.f, 0.f, 0.f};
    acc[0][0] = z; acc[0][1] = z; acc[1][0] = z; acc[1][1] = z;
    for (int ks = 0; ks < 8; ++ks) {
        int n0 = w * 256 + ks * 32 + l4 * 8;
        short8 a0 = *(const short8*)&kb[(size_t)l15 * N_DIM + n0];
        short8 a1 = *(const short8*)&kb[(size_t)(16 + l15) * N_DIM + n0];
        short8 b0 = *(const short8*)&vb[(size_t)l15 * N_DIM + n0];
        short8 b1 = *(const short8*)&vb[(size_t)(16 + l15) * N_DIM + n0];
        acc[0][0] = mfma16(a0, b0, acc[0][0]);
        acc[0][1] = mfma16(a0, b1, acc[0][1]);
        acc[1][0] = mfma16(a1, b0, acc[1][0]);
        acc[1][1] = mfma16(a1, b1, acc[1][1]);
    }
#pragma unroll
    for (int i = 0; i < 2; ++i)
#pragma unroll
        for (int j = 0; j < 2; ++j)
#pragma unroll
            for (int r = 0; r < 4; ++r)
                pbuf[w][i * 16 + l4 * 4 + r][j * 16 + l15] = acc[i][j][r];
    __syncthreads();
    // reduce across waves + hi/lo split into aop
    {
        int d1 = tid >> 3, d2 = (tid & 7) * 4;
        float4 s = make_float4(0.f, 0.f, 0.f, 0.f);
#pragma unroll
        for (int ww = 0; ww < 4; ++ww) {
            float4 p = *(const float4*)&pbuf[ww][d1][d2];
            s.x += p.x; s.y += p.y; s.z += p.z; s.w += p.w;
        }
        float xs[4] = {s.x, s.y, s.z, s.w};
#pragma unroll
        for (int q4 = 0; q4 < 4; ++q4) {
            __hip_bfloat16 hh = __float2bfloat16(xs[q4]);
            float hf = __bfloat162float(hh);
            __hip_bfloat16 ll = __float2bfloat16(xs[q4] - hf);
            aop[d1][d2 + q4] = *(unsigned short*)&hh;
            aop[32 + d1][d2 + q4] = *(unsigned short*)&ll;
        }
    }
    __syncthreads();
    // A-frags for ov (built once)
    short8 afr[2][2];
#pragma unroll
    for (int kk = 0; kk < 2; ++kk)
#pragma unroll
        for (int fm = 0; fm < 2; ++fm) {
            short8 v;
#pragma unroll
            for (int i = 0; i < 8; ++i)
                v[i] = (short)aop[kk * 32 + l4 * 8 + i][fm * 16 + l15];
            afr[kk][fm] = v;
        }
    const unsigned short* qb = sqT + (size_t)tb * CN;
    unsigned short* ob = soT + (size_t)tb * CN;
    // phase 2: o[c][n] per n-chunk of this wave
    for (int fn = 0; fn < 16; ++fn) {
        int n = w * 256 + fn * 16 + l15;
        short8 bq = *(const short8*)&qb[(size_t)n * C_DIM + h * 32 + l4 * 8];
        f32x4 o0 = z, o1 = z;
        o0 = mfma16(afr[0][0], bq, o0);
        o0 = mfma16(afr[1][0], bq, o0);
        o1 = mfma16(afr[0][1], bq, o1);
        o1 = mfma16(afr[1][1], bq, o1);
        ushort4 u0, u1;
        u0.x = bfbits(mspike(SCALE * o0[0]));
        u0.y = bfbits(mspike(SCALE * o0[1]));
        u0.z = bfbits(mspike(SCALE * o0[2]));
        u0.w = bfbits(mspike(SCALE * o0[3]));
        u1.x = bfbits(mspike(SCALE * o1[0]));
        u1.y = bfbits(mspike(SCALE * o1[1]));
        u1.z = bfbits(mspike(SCALE * o1[2]));
        u1.w = bfbits(mspike(SCALE * o1[3]));
        size_t obase = (size_t)n * C_DIM + h * 32 + l4 * 4;
        *(ushort4*)&ob[obase] = u0;
        *(ushort4*)&ob[obase + 16] = u1;
    }
}

extern "C" void kernel_launch(void* const* d_in, const int* in_sizes, int n_in,
                              void* d_out, int out_size, void* d_ws, size_t ws_size,
                              hipStream_t stream) {
    const float* query = (const float*)d_in[0];
    const float* qpos  = (const float*)d_in[3];
    const float* convw = (const float*)d_in[4];
    const float* convb = (const float*)d_in[5];
    const float* gam   = (const float*)d_in[6];
    const float* bet   = (const float*)d_in[7];
    const float* mn    = (const float*)d_in[8];
    const float* vr    = (const float*)d_in[9];
    float* out = (float*)d_out;

    char* ws = (char*)d_ws;
    float* tmp = (float*)ws;                                   // 8 MB f32
    unsigned short* sxT = (unsigned short*)(ws + (size_t)TOT * 4);
    unsigned short* sqT = sxT + TOT;
    unsigned short* skD = sqT + TOT;
    unsigned short* svD = skD + TOT;
    unsigned short* soT = svD + TOT;
    unsigned short* whl = soT + TOT;                           // 4*256*512
    float* bninv = (float*)(whl + 4 * 256 * 512);
    float* bnsh = bninv + 1024;

    prep_kernel<<<1024, 64, 0, stream>>>(convw, convb, gam, bet, mn, vr,
                                         whl, bninv, bnsh);
    add_spike_kernel<<<dim3(16, 4, 8), 256, 0, stream>>>(query, qpos, tmp, sxT);
    // q branch (n-major out)
    convbn_mfma<1, 0><<<dim3(1, 1, 128), 256, 0, stream>>>(
        whl, sxT, bninv, bnsh, sqT, nullptr, nullptr, nullptr, nullptr);
    // k,v branches (d-major out)
    convbn_mfma<2, 0><<<dim3(1, 1, 256), 256, 0, stream>>>(
        whl, sxT, bninv, bnsh, nullptr, skD, svD, nullptr, nullptr);
    // attention (exact kTv, split, PV)
    attn_kernel<<<64, 256, 0, stream>>>(skD, svD, sqT, soT);
    // final conv + residual (f32 out)
    convbn_mfma<2, 1><<<dim3(1, 1, 128), 256, 0, stream>>>(
        whl, soT, bninv, bnsh, nullptr, nullptr, nullptr, tmp, out);
}

// Round 3
// 48.286 us; speedup vs baseline: 2.2610x; 1.3358x over previous
//
#include <hip/hip_runtime.h>
#include <hip/hip_bf16.h>
#include <math.h>

#define N_DIM 1024
#define C_DIM 256
#define CN (C_DIM * N_DIM)
#define TOT (8 * CN)
#define BN_EPS 1e-5f
#define SCALE 0.1f

typedef short short8 __attribute__((ext_vector_type(8)));
typedef float f32x4 __attribute__((ext_vector_type(4)));

__device__ __forceinline__ float mspike(float x) {
    return rintf(fminf(fmaxf(x, 0.f), 4.f)) * 0.25f;
}
__device__ __forceinline__ unsigned short bfbits(float x) {
    __hip_bfloat16 h = __float2bfloat16(x);
    return *reinterpret_cast<unsigned short*>(&h);
}
__device__ __forceinline__ f32x4 mfma16(short8 a, short8 b, f32x4 c) {
    return __builtin_amdgcn_mfma_f32_16x16x32_bf16(a, b, c, 0, 0, 0);
}
__device__ __forceinline__ void async16(void* lds, const void* g) {
    __builtin_amdgcn_global_load_lds(
        (const __attribute__((address_space(1))) void*)g,
        (__attribute__((address_space(3))) void*)lds, 16, 0, 0);
}

// ---- L1: blocks 0..511 add+spike+transpose; blocks 512..767 weight prep ---
__global__ __launch_bounds__(256) void prep_spike_kernel(
    const float* __restrict__ q, const float* __restrict__ qp,
    const float* __restrict__ w, const float* __restrict__ cb,
    const float* __restrict__ g, const float* __restrict__ bet,
    const float* __restrict__ mn, const float* __restrict__ vr,
    float* __restrict__ tmp, unsigned short* __restrict__ sxT,
    unsigned short* __restrict__ whl, float* __restrict__ bninv,
    float* __restrict__ bnsh) {
    int bz = blockIdx.x, t = threadIdx.x;
    if (bz < 512) {
        __shared__ float ld[64][65];
        int tb = bz >> 6, c0 = ((bz >> 4) & 3) * 64, n0 = (bz & 15) * 64;
        int cl = t >> 4, nl = (t & 15) * 4;
        size_t base = (size_t)tb * CN;
#pragma unroll
        for (int r = 0; r < 4; ++r) {
            int c = cl + r * 16;
            size_t off = base + (size_t)(c0 + c) * N_DIM + n0 + nl;
            float4 a = *(const float4*)&q[off];
            float4 b = *(const float4*)&qp[off];
            float4 s = make_float4(a.x + b.x, a.y + b.y, a.z + b.z, a.w + b.w);
            *(float4*)&tmp[off] = s;
            ld[c][nl] = mspike(s.x); ld[c][nl + 1] = mspike(s.y);
            ld[c][nl + 2] = mspike(s.z); ld[c][nl + 3] = mspike(s.w);
        }
        __syncthreads();
        int nl2 = t >> 2, cg = (t & 3) * 16;
        size_t ob = base + (size_t)(n0 + nl2) * C_DIM + c0 + cg;
#pragma unroll
        for (int j = 0; j < 8; ++j) {
            ushort2 u = make_ushort2(bfbits(ld[cg + 2 * j][nl2]),
                                     bfbits(ld[cg + 2 * j + 1][nl2]));
            *(ushort2*)&sxT[ob + 2 * j] = u;
        }
    } else {
        int row = (bz - 512) * 4 + (t >> 6);
        int tl = t & 63;
        float4 wv = *(const float4*)&w[(size_t)row * 256 + tl * 4];
        float xs[4] = {wv.x, wv.y, wv.z, wv.w};
        unsigned short hi[4], lo[4];
#pragma unroll
        for (int j = 0; j < 4; ++j) {
            __hip_bfloat16 h = __float2bfloat16(xs[j]);
            float hf = __bfloat162float(h);
            __hip_bfloat16 l = __float2bfloat16(xs[j] - hf);
            hi[j] = *(unsigned short*)&h;
            lo[j] = *(unsigned short*)&l;
        }
        size_t base = (size_t)row * 512;
        *(ushort4*)&whl[base + tl * 4] = make_ushort4(hi[0], hi[1], hi[2], hi[3]);
        *(ushort4*)&whl[base + 256 + tl * 4] = make_ushort4(lo[0], lo[1], lo[2], lo[3]);
        if (tl == 0) {
            float inv = g[row] / sqrtf(vr[row] + BN_EPS);
            bninv[row] = inv;
            bnsh[row] = (cb[row] - mn[row]) * inv + bet[row];
        }
    }
}

// ---- conv_bn GEMM, 128x64 tile, BK=64, double-buffered, XOR-8 swizzle ----
// FIN=0: 768 blocks = q (ORIENT1, n-major bf16 out) + k,v (ORIENT2, d-major)
// FIN=1: 256 blocks = final branch (ORIENT2, f32 + residual)
template <int FIN>
__global__ __launch_bounds__(256) void conv_kernel(
    const unsigned short* __restrict__ whl,
    const unsigned short* __restrict__ actT,
    const float* __restrict__ bninv, const float* __restrict__ bnsh,
    unsigned short* __restrict__ dq, unsigned short* __restrict__ dk,
    unsigned short* __restrict__ dv, const float* __restrict__ tmp,
    float* __restrict__ outf) {
    __shared__ short At[2][128 * 64];
    __shared__ short Bt[2][64 * 64];
    int bz = blockIdx.x;
    int orient, br, tb, m0, n0;
    if (FIN) {
        orient = 2; br = 3;
        tb = bz >> 5; m0 = ((bz >> 2) & 7) * 128; n0 = (bz & 3) * 64;
    } else if (bz < 256) {
        orient = 1; br = 0;
        tb = bz >> 5; m0 = ((bz >> 4) & 1) * 128; n0 = (bz & 15) * 64;
    } else {
        int r = bz - 256;
        orient = 2; br = 1 + (r >> 8); r &= 255;
        tb = r >> 5; m0 = ((r >> 2) & 7) * 128; n0 = (r & 3) * 64;
    }
    const int tid = threadIdx.x, lane = tid & 63, wid = tid >> 6;
    const int wm = wid >> 1, wn = wid & 1;
    const int l15 = lane & 15, l4 = lane >> 4;
    const unsigned short* wbase = whl + (size_t)br * 131072;
    const unsigned short* abase = actT + (size_t)tb * CN;

    // per-thread staging source pointers (pre-swizzled), k-offset added per kt
    const unsigned short* pa[4];
    const unsigned short* pb[2];
#pragma unroll
    for (int c = 0; c < 4; ++c) {
        int s = c * 256 + tid;
        int row = s >> 3, gsw = ((s & 7) ^ (row & 7)) * 8;
        pa[c] = (orient == 1) ? wbase + (size_t)(m0 + row) * 512 + gsw
                              : abase + (size_t)(m0 + row) * 256 + gsw;
    }
#pragma unroll
    for (int c = 0; c < 2; ++c) {
        int s = c * 256 + tid;
        int row = s >> 3, gsw = ((s & 7) ^ (row & 7)) * 8;
        pb[c] = (orient == 1) ? abase + (size_t)(n0 + row) * 256 + gsw
                              : wbase + (size_t)(n0 + row) * 512 + gsw;
    }

    f32x4 acc[4][2];
    f32x4 z = {0.f, 0.f, 0.f, 0.f};
#pragma unroll
    for (int i = 0; i < 4; ++i) { acc[i][0] = z; acc[i][1] = z; }

    auto stage = [&](int buf, int kt) {
        int kw = kt * 64, ka = (kt & 3) * 64;
        int offA = (orient == 1) ? kw : ka;
        int offB = (orient == 1) ? ka : kw;
#pragma unroll
        for (int c = 0; c < 4; ++c)
            async16(&At[buf][(c * 256 + tid) * 8], pa[c] + offA);
#pragma unroll
        for (int c = 0; c < 2; ++c)
            async16(&Bt[buf][(c * 256 + tid) * 8], pb[c] + offB);
    };

    stage(0, 0);
    __syncthreads();
    int cur = 0;
    for (int kt = 0; kt < 8; ++kt) {
        if (kt < 7) stage(cur ^ 1, kt + 1);
#pragma unroll
        for (int kk = 0; kk < 2; ++kk) {
            short8 af[4], bf[2];
#pragma unroll
            for (int f = 0; f < 4; ++f) {
                int rowa = wm * 64 + f * 16 + l15;
                int ka = ((kk * 4 + l4) ^ (rowa & 7)) << 4;
                af[f] = *(const short8*)((const char*)&At[cur][0] + rowa * 128 + ka);
            }
#pragma unroll
            for (int f = 0; f < 2; ++f) {
                int rowb = wn * 32 + f * 16 + l15;
                int kb2 = ((kk * 4 + l4) ^ (rowb & 7)) << 4;
                bf[f] = *(const short8*)((const char*)&Bt[cur][0] + rowb * 128 + kb2);
            }
#pragma unroll
            for (int i = 0; i < 4; ++i) {
                acc[i][0] = mfma16(af[i], bf[0], acc[i][0]);
                acc[i][1] = mfma16(af[i], bf[1], acc[i][1]);
            }
        }
        __syncthreads();
        cur ^= 1;
    }

    if (orient == 1) {
#pragma unroll
        for (int i = 0; i < 4; ++i) {
            int cb4 = m0 + wm * 64 + i * 16 + l4 * 4;
            float4 inv = *(const float4*)&bninv[cb4];
            float4 sh = *(const float4*)&bnsh[cb4];
#pragma unroll
            for (int j = 0; j < 2; ++j) {
                int n = n0 + wn * 32 + j * 16 + l15;
                f32x4 a = acc[i][j];
                ushort4 u;
                u.x = bfbits(mspike(a[0] * inv.x + sh.x));
                u.y = bfbits(mspike(a[1] * inv.y + sh.y));
                u.z = bfbits(mspike(a[2] * inv.z + sh.z));
                u.w = bfbits(mspike(a[3] * inv.w + sh.w));
                *(ushort4*)&dq[(size_t)tb * CN + (size_t)n * C_DIM + cb4] = u;
            }
        }
    } else {
#pragma unroll
        for (int j = 0; j < 2; ++j) {
            int c = n0 + wn * 32 + j * 16 + l15;
            float inv = bninv[br * 256 + c];
            float sh = bnsh[br * 256 + c];
#pragma unroll
            for (int i = 0; i < 4; ++i) {
                int nb4 = m0 + wm * 64 + i * 16 + l4 * 4;
                f32x4 a = acc[i][j];
                size_t off = (size_t)tb * CN + (size_t)c * N_DIM + nb4;
                if (!FIN) {
                    ushort4 u;
                    u.x = bfbits(mspike(a[0] * inv + sh));
                    u.y = bfbits(mspike(a[1] * inv + sh));
                    u.z = bfbits(mspike(a[2] * inv + sh));
                    u.w = bfbits(mspike(a[3] * inv + sh));
                    unsigned short* dst = (br == 1) ? dk : dv;
                    *(ushort4*)&dst[off] = u;
                } else {
                    float4 t4 = *(const float4*)&tmp[off];
                    float4 o;
                    o.x = a[0] * inv + sh + t4.x;
                    o.y = a[1] * inv + sh + t4.y;
                    o.z = a[2] * inv + sh + t4.z;
                    o.w = a[3] * inv + sh + t4.w;
                    *(float4*)&outf[off] = o;
                }
            }
        }
    }
}

// ---- attention: per (head, n-chunk) block; kTv exact + hi/lo split + PV ---
__global__ __launch_bounds__(256) void attn_kernel(
    const unsigned short* __restrict__ skD, const unsigned short* __restrict__ svD,
    const unsigned short* __restrict__ sqT, unsigned short* __restrict__ soT) {
    __shared__ float pbuf[4][32][33];
    __shared__ unsigned short aop[64][32];
    int tbh = blockIdx.x >> 2, nc = blockIdx.x & 3;
    int tb = tbh >> 3, h = tbh & 7;
    int tid = threadIdx.x, lane = tid & 63, w = tid >> 6;
    int l15 = lane & 15, l4 = lane >> 4;
    const unsigned short* kb = skD + (size_t)tb * CN + (size_t)h * 32 * N_DIM;
    const unsigned short* vb = svD + (size_t)tb * CN + (size_t)h * 32 * N_DIM;

    f32x4 acc[2][2];
    f32x4 z = {0.f, 0.f, 0.f, 0.f};
    acc[0][0] = z; acc[0][1] = z; acc[1][0] = z; acc[1][1] = z;
    for (int ks = 0; ks < 8; ++ks) {
        int n0 = w * 256 + ks * 32 + l4 * 8;
        short8 a0 = *(const short8*)&kb[(size_t)l15 * N_DIM + n0];
        short8 a1 = *(const short8*)&kb[(size_t)(16 + l15) * N_DIM + n0];
        short8 b0 = *(const short8*)&vb[(size_t)l15 * N_DIM + n0];
        short8 b1 = *(const short8*)&vb[(size_t)(16 + l15) * N_DIM + n0];
        acc[0][0] = mfma16(a0, b0, acc[0][0]);
        acc[0][1] = mfma16(a0, b1, acc[0][1]);
        acc[1][0] = mfma16(a1, b0, acc[1][0]);
        acc[1][1] = mfma16(a1, b1, acc[1][1]);
    }
#pragma unroll
    for (int i = 0; i < 2; ++i)
#pragma unroll
        for (int j = 0; j < 2; ++j)
#pragma unroll
            for (int r = 0; r < 4; ++r)
                pbuf[w][i * 16 + l4 * 4 + r][j * 16 + l15] = acc[i][j][r];
    __syncthreads();
    {
        int d1 = tid >> 3, d2 = (tid & 7) * 4;
        float4 s = make_float4(0.f, 0.f, 0.f, 0.f);
#pragma unroll
        for (int ww = 0; ww < 4; ++ww) {
            float4 p = *(const float4*)&pbuf[ww][d1][d2];
            s.x += p.x; s.y += p.y; s.z += p.z; s.w += p.w;
        }
        float xs[4] = {s.x, s.y, s.z, s.w};
#pragma unroll
        for (int q4 = 0; q4 < 4; ++q4) {
            __hip_bfloat16 hh = __float2bfloat16(xs[q4]);
            float hf = __bfloat162float(hh);
            __hip_bfloat16 ll = __float2bfloat16(xs[q4] - hf);
            aop[d1][d2 + q4] = *(unsigned short*)&hh;
            aop[32 + d1][d2 + q4] = *(unsigned short*)&ll;
        }
    }
    __syncthreads();
    short8 afr[2][2];
#pragma unroll
    for (int kk = 0; kk < 2; ++kk)
#pragma unroll
        for (int fm = 0; fm < 2; ++fm) {
            short8 v;
#pragma unroll
            for (int i = 0; i < 8; ++i)
                v[i] = (short)aop[kk * 32 + l4 * 8 + i][fm * 16 + l15];
            afr[kk][fm] = v;
        }
    const unsigned short* qb = sqT + (size_t)tb * CN;
    unsigned short* ob = soT + (size_t)tb * CN;
#pragma unroll
    for (int fn = 0; fn < 4; ++fn) {
        int n = nc * 256 + w * 64 + fn * 16 + l15;
        short8 bq = *(const short8*)&qb[(size_t)n * C_DIM + h * 32 + l4 * 8];
        f32x4 o0 = z, o1 = z;
        o0 = mfma16(afr[0][0], bq, o0);
        o0 = mfma16(afr[1][0], bq, o0);
        o1 = mfma16(afr[0][1], bq, o1);
        o1 = mfma16(afr[1][1], bq, o1);
        ushort4 u0, u1;
        u0.x = bfbits(mspike(SCALE * o0[0]));
        u0.y = bfbits(mspike(SCALE * o0[1]));
        u0.z = bfbits(mspike(SCALE * o0[2]));
        u0.w = bfbits(mspike(SCALE * o0[3]));
        u1.x = bfbits(mspike(SCALE * o1[0]));
        u1.y = bfbits(mspike(SCALE * o1[1]));
        u1.z = bfbits(mspike(SCALE * o1[2]));
        u1.w = bfbits(mspike(SCALE * o1[3]));
        size_t obase = (size_t)n * C_DIM + h * 32 + l4 * 4;
        *(ushort4*)&ob[obase] = u0;
        *(ushort4*)&ob[obase + 16] = u1;
    }
}

extern "C" void kernel_launch(void* const* d_in, const int* in_sizes, int n_in,
                              void* d_out, int out_size, void* d_ws, size_t ws_size,
                              hipStream_t stream) {
    const float* query = (const float*)d_in[0];
    const float* qpos  = (const float*)d_in[3];
    const float* convw = (const float*)d_in[4];
    const float* convb = (const float*)d_in[5];
    const float* gam   = (const float*)d_in[6];
    const float* bet   = (const float*)d_in[7];
    const float* mn    = (const float*)d_in[8];
    const float* vr    = (const float*)d_in[9];
    float* out = (float*)d_out;

    char* ws = (char*)d_ws;
    float* tmp = (float*)ws;
    unsigned short* sxT = (unsigned short*)(ws + (size_t)TOT * 4);
    unsigned short* sqT = sxT + TOT;
    unsigned short* skD = sqT + TOT;
    unsigned short* svD = skD + TOT;
    unsigned short* soT = svD + TOT;
    unsigned short* whl = soT + TOT;
    float* bninv = (float*)(whl + 4 * 256 * 512);
    float* bnsh = bninv + 1024;

    prep_spike_kernel<<<768, 256, 0, stream>>>(
        query, qpos, convw, convb, gam, bet, mn, vr, tmp, sxT, whl, bninv, bnsh);
    conv_kernel<0><<<768, 256, 0, stream>>>(
        whl, sxT, bninv, bnsh, sqT, skD, svD, nullptr, nullptr);
    attn_kernel<<<256, 256, 0, stream>>>(skD, svD, sqT, soT);
    conv_kernel<1><<<256, 256, 0, stream>>>(
        whl, soT, bninv, bnsh, nullptr, nullptr, nullptr, tmp, out);
}

// Round 4
// 43.471 us; speedup vs baseline: 2.5115x; 1.1108x over previous
//
#include <hip/hip_runtime.h>
#include <hip/hip_bf16.h>
#include <math.h>

#define N_DIM 1024
#define C_DIM 256
#define CN (C_DIM * N_DIM)
#define TOT (8 * CN)
#define BN_EPS 1e-5f
#define SCALE 0.1f

typedef short short8 __attribute__((ext_vector_type(8)));
typedef float f32x4 __attribute__((ext_vector_type(4)));

__device__ __forceinline__ float mspike(float x) {
    return rintf(fminf(fmaxf(x, 0.f), 4.f)) * 0.25f;
}
__device__ __forceinline__ unsigned short bfbits(float x) {
    __hip_bfloat16 h = __float2bfloat16(x);
    return *reinterpret_cast<unsigned short*>(&h);
}
__device__ __forceinline__ f32x4 mfma16(short8 a, short8 b, f32x4 c) {
    return __builtin_amdgcn_mfma_f32_16x16x32_bf16(a, b, c, 0, 0, 0);
}
__device__ __forceinline__ void async16(void* lds, const void* g) {
    __builtin_amdgcn_global_load_lds(
        (const __attribute__((address_space(1))) void*)g,
        (__attribute__((address_space(3))) void*)lds, 16, 0, 0);
}

// ---- L1 (512 blocks): add+spike+transpose tile + 2 weight rows per block --
// XCD swizzle: logical = (bz&7)*64 + bz>>3; tb = logical>>6 -> xcd == tb
__global__ __launch_bounds__(256) void prep_spike_kernel(
    const float* __restrict__ q, const float* __restrict__ qp,
    const float* __restrict__ w, const float* __restrict__ cb,
    const float* __restrict__ g, const float* __restrict__ bet,
    const float* __restrict__ mn, const float* __restrict__ vr,
    float* __restrict__ tmp, unsigned short* __restrict__ sxT,
    unsigned short* __restrict__ whl, float* __restrict__ bninv,
    float* __restrict__ bnsh) {
    int logical = ((blockIdx.x & 7) << 6) + (blockIdx.x >> 3);
    int t = threadIdx.x;
    __shared__ float ld[64][65];
    {
        int tb = logical >> 6, u = logical & 63;
        int c0 = (u >> 4) * 64, n0 = (u & 15) * 64;
        int cl = t >> 4, nl = (t & 15) * 4;
        size_t base = (size_t)tb * CN;
#pragma unroll
        for (int r = 0; r < 4; ++r) {
            int c = cl + r * 16;
            size_t off = base + (size_t)(c0 + c) * N_DIM + n0 + nl;
            float4 a = *(const float4*)&q[off];
            float4 b = *(const float4*)&qp[off];
            float4 s = make_float4(a.x + b.x, a.y + b.y, a.z + b.z, a.w + b.w);
            *(float4*)&tmp[off] = s;
            ld[c][nl] = mspike(s.x); ld[c][nl + 1] = mspike(s.y);
            ld[c][nl + 2] = mspike(s.z); ld[c][nl + 3] = mspike(s.w);
        }
        __syncthreads();
        int nl2 = t >> 2, cg = (t & 3) * 16;
        size_t ob = base + (size_t)(n0 + nl2) * C_DIM + c0 + cg;
#pragma unroll
        for (int j = 0; j < 8; ++j) {
            ushort2 u2 = make_ushort2(bfbits(ld[cg + 2 * j][nl2]),
                                      bfbits(ld[cg + 2 * j + 1][nl2]));
            *(ushort2*)&sxT[ob + 2 * j] = u2;
        }
    }
    // weight prep: rows 2*logical, 2*logical+1 (1024 rows total)
    {
        int row = 2 * logical + (t >> 7);
        int tl = t & 127;
        float2 wv = *(const float2*)&w[(size_t)row * 256 + tl * 2];
        __hip_bfloat16 h0 = __float2bfloat16(wv.x);
        __hip_bfloat16 h1 = __float2bfloat16(wv.y);
        __hip_bfloat16 l0 = __float2bfloat16(wv.x - __bfloat162float(h0));
        __hip_bfloat16 l1 = __float2bfloat16(wv.y - __bfloat162float(h1));
        size_t base = (size_t)row * 512;
        *(ushort2*)&whl[base + tl * 2] =
            make_ushort2(*(unsigned short*)&h0, *(unsigned short*)&h1);
        *(ushort2*)&whl[base + 256 + tl * 2] =
            make_ushort2(*(unsigned short*)&l0, *(unsigned short*)&l1);
        if (tl == 0) {
            float inv = g[row] / sqrtf(vr[row] + BN_EPS);
            bninv[row] = inv;
            bnsh[row] = (cb[row] - mn[row]) * inv + bet[row];
        }
    }
}

// ---- conv GEMM. FIN=0 (512 blocks): q tiles (orient1) + fused k&v tiles.
// FIN=1 (256 blocks): final branch + residual, f32 out.
// XCD swizzle keeps each tb on one XCD.
template <int FIN>
__global__ __launch_bounds__(256) void conv_kernel(
    const unsigned short* __restrict__ whl,
    const unsigned short* __restrict__ actT,
    const float* __restrict__ bninv, const float* __restrict__ bnsh,
    unsigned short* __restrict__ dq, unsigned short* __restrict__ dk,
    unsigned short* __restrict__ dv, const float* __restrict__ tmp,
    float* __restrict__ outf) {
    __shared__ short At[2][128 * 64];
    __shared__ short Bt[2][2][64 * 64];
    int bz = blockIdx.x;
    int tb, m0, n0;
    bool isQ = false;
    if (FIN) {
        int logical = ((bz & 7) << 5) + (bz >> 3);
        tb = logical >> 5;
        int u = logical & 31;
        m0 = (u >> 2) * 128; n0 = (u & 3) * 64;
    } else {
        int logical = ((bz & 7) << 6) + (bz >> 3);
        tb = logical >> 6;
        int u = logical & 63;
        if (u < 32) { isQ = true; m0 = ((u >> 4) & 1) * 128; n0 = (u & 15) * 64; }
        else { u -= 32; m0 = (u >> 2) * 128; n0 = (u & 3) * 64; }
    }
    const int tid = threadIdx.x, lane = tid & 63, wid = tid >> 6;
    const int wm = wid >> 1, wn = wid & 1;
    const int l15 = lane & 15, l4 = lane >> 4;
    const unsigned short* abase = actT + (size_t)tb * CN;
    f32x4 z = {0.f, 0.f, 0.f, 0.f};

    if (!FIN && isQ) {
        // ---------------- q branch: A = W0, B = act ----------------
        const unsigned short* wbase = whl;
        const unsigned short* pa[4];
        const unsigned short* pb[2];
#pragma unroll
        for (int c = 0; c < 4; ++c) {
            int s = c * 256 + tid, row = s >> 3, gsw = ((s & 7) ^ (row & 7)) * 8;
            pa[c] = wbase + (size_t)(m0 + row) * 512 + gsw;
        }
#pragma unroll
        for (int c = 0; c < 2; ++c) {
            int s = c * 256 + tid, row = s >> 3, gsw = ((s & 7) ^ (row & 7)) * 8;
            pb[c] = abase + (size_t)(n0 + row) * 256 + gsw;
        }
        f32x4 acc[4][2];
#pragma unroll
        for (int i = 0; i < 4; ++i) { acc[i][0] = z; acc[i][1] = z; }
        auto stage = [&](int buf, int kt) {
            int kw = kt * 64, ka = (kt & 3) * 64;
#pragma unroll
            for (int c = 0; c < 4; ++c)
                async16(&At[buf][(c * 256 + tid) * 8], pa[c] + kw);
#pragma unroll
            for (int c = 0; c < 2; ++c)
                async16(&Bt[buf][0][(c * 256 + tid) * 8], pb[c] + ka);
        };
        stage(0, 0);
        __syncthreads();
        int cur = 0;
        for (int kt = 0; kt < 8; ++kt) {
            if (kt < 7) stage(cur ^ 1, kt + 1);
#pragma unroll
            for (int kk = 0; kk < 2; ++kk) {
                short8 af[4], bf[2];
#pragma unroll
                for (int f = 0; f < 4; ++f) {
                    int rowa = wm * 64 + f * 16 + l15;
                    int ka = ((kk * 4 + l4) ^ (rowa & 7)) << 4;
                    af[f] = *(const short8*)((const char*)&At[cur][0] + rowa * 128 + ka);
                }
#pragma unroll
                for (int f = 0; f < 2; ++f) {
                    int rowb = wn * 32 + f * 16 + l15;
                    int kb2 = ((kk * 4 + l4) ^ (rowb & 7)) << 4;
                    bf[f] = *(const short8*)((const char*)&Bt[cur][0][0] + rowb * 128 + kb2);
                }
#pragma unroll
                for (int i = 0; i < 4; ++i) {
                    acc[i][0] = mfma16(af[i], bf[0], acc[i][0]);
                    acc[i][1] = mfma16(af[i], bf[1], acc[i][1]);
                }
            }
            __syncthreads();
            cur ^= 1;
        }
#pragma unroll
        for (int i = 0; i < 4; ++i) {
            int cb4 = m0 + wm * 64 + i * 16 + l4 * 4;
            float4 inv = *(const float4*)&bninv[cb4];
            float4 sh = *(const float4*)&bnsh[cb4];
#pragma unroll
            for (int j = 0; j < 2; ++j) {
                int n = n0 + wn * 32 + j * 16 + l15;
                f32x4 a = acc[i][j];
                ushort4 u4;
                u4.x = bfbits(mspike(a[0] * inv.x + sh.x));
                u4.y = bfbits(mspike(a[1] * inv.y + sh.y));
                u4.z = bfbits(mspike(a[2] * inv.z + sh.z));
                u4.w = bfbits(mspike(a[3] * inv.w + sh.w));
                *(ushort4*)&dq[(size_t)tb * CN + (size_t)n * C_DIM + cb4] = u4;
            }
        }
    } else {
        // -------- orient2: A = act; B = {k,v} weights (FIN: proj) --------
        const int NB = FIN ? 1 : 2;
        const int brbase = FIN ? 3 : 1;
        const unsigned short* pa[4];
        const unsigned short* pb[2][2];
#pragma unroll
        for (int c = 0; c < 4; ++c) {
            int s = c * 256 + tid, row = s >> 3, gsw = ((s & 7) ^ (row & 7)) * 8;
            pa[c] = abase + (size_t)(m0 + row) * 256 + gsw;
        }
#pragma unroll
        for (int b = 0; b < NB; ++b)
#pragma unroll
            for (int c = 0; c < 2; ++c) {
                int s = c * 256 + tid, row = s >> 3, gsw = ((s & 7) ^ (row & 7)) * 8;
                pb[b][c] = whl + (size_t)(brbase + b) * 131072 +
                           (size_t)(n0 + row) * 512 + gsw;
            }
        f32x4 acc[2][4][2];
#pragma unroll
        for (int b = 0; b < NB; ++b)
#pragma unroll
            for (int i = 0; i < 4; ++i) { acc[b][i][0] = z; acc[b][i][1] = z; }
        auto stage = [&](int buf, int kt) {
            int kw = kt * 64, ka = (kt & 3) * 64;
#pragma unroll
            for (int c = 0; c < 4; ++c)
                async16(&At[buf][(c * 256 + tid) * 8], pa[c] + ka);
#pragma unroll
            for (int b = 0; b < NB; ++b)
#pragma unroll
                for (int c = 0; c < 2; ++c)
                    async16(&Bt[buf][b][(c * 256 + tid) * 8], pb[b][c] + kw);
        };
        stage(0, 0);
        __syncthreads();
        int cur = 0;
        for (int kt = 0; kt < 8; ++kt) {
            if (kt < 7) stage(cur ^ 1, kt + 1);
#pragma unroll
            for (int kk = 0; kk < 2; ++kk) {
                short8 af[4];
#pragma unroll
                for (int f = 0; f < 4; ++f) {
                    int rowa = wm * 64 + f * 16 + l15;
                    int ka = ((kk * 4 + l4) ^ (rowa & 7)) << 4;
                    af[f] = *(const short8*)((const char*)&At[cur][0] + rowa * 128 + ka);
                }
#pragma unroll
                for (int b = 0; b < NB; ++b) {
                    short8 bf[2];
#pragma unroll
                    for (int f = 0; f < 2; ++f) {
                        int rowb = wn * 32 + f * 16 + l15;
                        int kb2 = ((kk * 4 + l4) ^ (rowb & 7)) << 4;
                        bf[f] = *(const short8*)((const char*)&Bt[cur][b][0] + rowb * 128 + kb2);
                    }
#pragma unroll
                    for (int i = 0; i < 4; ++i) {
                        acc[b][i][0] = mfma16(af[i], bf[0], acc[b][i][0]);
                        acc[b][i][1] = mfma16(af[i], bf[1], acc[b][i][1]);
                    }
                }
            }
            __syncthreads();
            cur ^= 1;
        }
#pragma unroll
        for (int b = 0; b < NB; ++b) {
#pragma unroll
            for (int j = 0; j < 2; ++j) {
                int c = n0 + wn * 32 + j * 16 + l15;
                float inv = bninv[(brbase + b) * 256 + c];
                float sh = bnsh[(brbase + b) * 256 + c];
#pragma unroll
                for (int i = 0; i < 4; ++i) {
                    int nb4 = m0 + wm * 64 + i * 16 + l4 * 4;
                    f32x4 a = acc[b][i][j];
                    size_t off = (size_t)tb * CN + (size_t)c * N_DIM + nb4;
                    if (!FIN) {
                        ushort4 u4;
                        u4.x = bfbits(mspike(a[0] * inv + sh));
                        u4.y = bfbits(mspike(a[1] * inv + sh));
                        u4.z = bfbits(mspike(a[2] * inv + sh));
                        u4.w = bfbits(mspike(a[3] * inv + sh));
                        unsigned short* dst = (b == 0) ? dk : dv;
                        *(ushort4*)&dst[off] = u4;
                    } else {
                        float4 t4 = *(const float4*)&tmp[off];
                        float4 o;
                        o.x = a[0] * inv + sh + t4.x;
                        o.y = a[1] * inv + sh + t4.y;
                        o.z = a[2] * inv + sh + t4.z;
                        o.w = a[3] * inv + sh + t4.w;
                        *(float4*)&outf[off] = o;
                    }
                }
            }
        }
    }
}

// ---- attention (256 blocks): kTv exact + hi/lo split + PV; swizzled ------
__global__ __launch_bounds__(256) void attn_kernel(
    const unsigned short* __restrict__ skD, const unsigned short* __restrict__ svD,
    const unsigned short* __restrict__ sqT, unsigned short* __restrict__ soT) {
    __shared__ float pbuf[4][32][33];
    __shared__ unsigned short aop[64][32];
    int logical = ((blockIdx.x & 7) << 5) + (blockIdx.x >> 3);
    int tb = logical >> 5, u = logical & 31;
    int h = u >> 2, nc = u & 3;
    int tid = threadIdx.x, lane = tid & 63, w = tid >> 6;
    int l15 = lane & 15, l4 = lane >> 4;
    const unsigned short* kb = skD + (size_t)tb * CN + (size_t)h * 32 * N_DIM;
    const unsigned short* vb = svD + (size_t)tb * CN + (size_t)h * 32 * N_DIM;
    f32x4 z = {0.f, 0.f, 0.f, 0.f};

    f32x4 acc[2][2];
    acc[0][0] = z; acc[0][1] = z; acc[1][0] = z; acc[1][1] = z;
    for (int ks = 0; ks < 8; ++ks) {
        int n0 = w * 256 + ks * 32 + l4 * 8;
        short8 a0 = *(const short8*)&kb[(size_t)l15 * N_DIM + n0];
        short8 a1 = *(const short8*)&kb[(size_t)(16 + l15) * N_DIM + n0];
        short8 b0 = *(const short8*)&vb[(size_t)l15 * N_DIM + n0];
        short8 b1 = *(const short8*)&vb[(size_t)(16 + l15) * N_DIM + n0];
        acc[0][0] = mfma16(a0, b0, acc[0][0]);
        acc[0][1] = mfma16(a0, b1, acc[0][1]);
        acc[1][0] = mfma16(a1, b0, acc[1][0]);
        acc[1][1] = mfma16(a1, b1, acc[1][1]);
    }
#pragma unroll
    for (int i = 0; i < 2; ++i)
#pragma unroll
        for (int j = 0; j < 2; ++j)
#pragma unroll
            for (int r = 0; r < 4; ++r)
                pbuf[w][i * 16 + l4 * 4 + r][j * 16 + l15] = acc[i][j][r];
    __syncthreads();
    {
        int d1 = tid >> 3, d2 = (tid & 7) * 4;
        float4 s = make_float4(0.f, 0.f, 0.f, 0.f);
#pragma unroll
        for (int ww = 0; ww < 4; ++ww) {
            float4 p = *(const float4*)&pbuf[ww][d1][d2];
            s.x += p.x; s.y += p.y; s.z += p.z; s.w += p.w;
        }
        float xs[4] = {s.x, s.y, s.z, s.w};
#pragma unroll
        for (int q4 = 0; q4 < 4; ++q4) {
            __hip_bfloat16 hh = __float2bfloat16(xs[q4]);
            float hf = __bfloat162float(hh);
            __hip_bfloat16 ll = __float2bfloat16(xs[q4] - hf);
            aop[d1][d2 + q4] = *(unsigned short*)&hh;
            aop[32 + d1][d2 + q4] = *(unsigned short*)&ll;
        }
    }
    __syncthreads();
    short8 afr[2][2];
#pragma unroll
    for (int kk = 0; kk < 2; ++kk)
#pragma unroll
        for (int fm = 0; fm < 2; ++fm) {
            short8 v;
#pragma unroll
            for (int i = 0; i < 8; ++i)
                v[i] = (short)aop[kk * 32 + l4 * 8 + i][fm * 16 + l15];
            afr[kk][fm] = v;
        }
    const unsigned short* qb = sqT + (size_t)tb * CN;
    unsigned short* ob = soT + (size_t)tb * CN;
#pragma unroll
    for (int fn = 0; fn < 4; ++fn) {
        int n = nc * 256 + w * 64 + fn * 16 + l15;
        short8 bq = *(const short8*)&qb[(size_t)n * C_DIM + h * 32 + l4 * 8];
        f32x4 o0 = z, o1 = z;
        o0 = mfma16(afr[0][0], bq, o0);
        o0 = mfma16(afr[1][0], bq, o0);
        o1 = mfma16(afr[0][1], bq, o1);
        o1 = mfma16(afr[1][1], bq, o1);
        ushort4 u0, u1;
        u0.x = bfbits(mspike(SCALE * o0[0]));
        u0.y = bfbits(mspike(SCALE * o0[1]));
        u0.z = bfbits(mspike(SCALE * o0[2]));
        u0.w = bfbits(mspike(SCALE * o0[3]));
        u1.x = bfbits(mspike(SCALE * o1[0]));
        u1.y = bfbits(mspike(SCALE * o1[1]));
        u1.z = bfbits(mspike(SCALE * o1[2]));
        u1.w = bfbits(mspike(SCALE * o1[3]));
        size_t obase = (size_t)n * C_DIM + h * 32 + l4 * 4;
        *(ushort4*)&ob[obase] = u0;
        *(ushort4*)&ob[obase + 16] = u1;
    }
}

extern "C" void kernel_launch(void* const* d_in, const int* in_sizes, int n_in,
                              void* d_out, int out_size, void* d_ws, size_t ws_size,
                              hipStream_t stream) {
    const float* query = (const float*)d_in[0];
    const float* qpos  = (const float*)d_in[3];
    const float* convw = (const float*)d_in[4];
    const float* convb = (const float*)d_in[5];
    const float* gam   = (const float*)d_in[6];
    const float* bet   = (const float*)d_in[7];
    const float* mn    = (const float*)d_in[8];
    const float* vr    = (const float*)d_in[9];
    float* out = (float*)d_out;

    char* ws = (char*)d_ws;
    float* tmp = (float*)ws;
    unsigned short* sxT = (unsigned short*)(ws + (size_t)TOT * 4);
    unsigned short* sqT = sxT + TOT;
    unsigned short* skD = sqT + TOT;
    unsigned short* svD = skD + TOT;
    unsigned short* soT = svD + TOT;
    unsigned short* whl = soT + TOT;
    float* bninv = (float*)(whl + 4 * 256 * 512);
    float* bnsh = bninv + 1024;

    prep_spike_kernel<<<512, 256, 0, stream>>>(
        query, qpos, convw, convb, gam, bet, mn, vr, tmp, sxT, whl, bninv, bnsh);
    conv_kernel<0><<<512, 256, 0, stream>>>(
        whl, sxT, bninv, bnsh, sqT, skD, svD, nullptr, nullptr);
    attn_kernel<<<256, 256, 0, stream>>>(skD, svD, sqT, soT);
    conv_kernel<1><<<256, 256, 0, stream>>>(
        whl, soT, bninv, bnsh, nullptr, nullptr, nullptr, tmp, out);
}